// Round 2
// baseline (176.214 us; speedup 1.0000x reference)
//
#include <hip/hip_runtime.h>
#include <math.h>

// ---------------------------------------------------------------------------
// GaussianQuant — MFMA-filtered argmax, R15.
// score[n,k] = sum_d p*c + q*c^2;  u=[p,q], v=[c,c^2], score = u.v  (K=64)
// fp16 HI-ONLY approx: |err| <= 1.05e-3*S (rigorous), S = sum |p|M1+|q|M1^2.
// R15 (vs R14): filter restructured from LDS-staged (block owns 1024 k,
// streams B through LDS with 8 chunk barriers) to REGISTER-RESIDENT B:
//   - block owns 128 k  -> B panel = 8 tiles x 2 half8 = 64 VGPR, loaded ONCE
//   - wave streams 512 rows of A from L2 (prefetch 1 rowtile ahead)
//   - ZERO barriers, ZERO LDS, pure MFMA+VALU dual-pipe stream
//   - grid (8 rowgroups, 128 kblks): linear%8 = rowgroup = XCD, so each XCD
//     L2-caches exactly its 256-KB A-quarter (read 128x) and all of B (2 MB)
// Columns become 64 CONSECUTIVE k (col = k>>6): filter folds c16 lanes by
// shuffle-max; merge rescans read 64 consecutive cb lines (coalesced).
// W1 layout [col][row]: block-exclusive contiguous writes. Merge rows are
// XCD-chunk swizzled so blocks sharing W1 sectors share an L2.
// Error bound & two-phase merge prune semantics UNCHANGED from R14.
// ---------------------------------------------------------------------------

typedef _Float16 half8 __attribute__((ext_vector_type(8)));
typedef float f32x4 __attribute__((ext_vector_type(4)));

#define DIM 32
#define NROWS 16384
#define KSIZE 16384
#define KBLK 128                        // k per filter block (2 cols of 64)
#define NKB (KSIZE / KBLK)              // 128
#define RGRP 8                          // row groups (one per XCD)
#define NRT 32                          // rowtiles/wave = 16384/RGRP/4/16
#define NCOL 256                        // columns = 64-k groups

// ws layout (bytes); [0,4096) zeroed by memset each launch
#define WS_M1   0                       // 32 float (atomicMax targets)
#define WS_KL   256                     // 1 double (atomicAdd target)
#define WS_PQ   4096                    // 4 MB fp32 [row][64]
#define WS_AH   (WS_PQ + 4194304)       // 2 MB fp16 [row][64]
#define WS_BH   (WS_AH + 2097152)       // 2 MB fp16 [k][64] LINEAR
#define WS_W1   (WS_BH + 2097152)       // 16 MB fp32 [col][row]

// Fused prep, 1024 blocks: [0,512) pack codebook (linear) + per-dim max;
// [512,1024) compute p,q + fp16 pack + KL partial sum.
__global__ __launch_bounds__(256) void prep_kernel(const float* __restrict__ cb,
                                                   const float* __restrict__ z,
                                                   _Float16* __restrict__ Bh,
                                                   float* __restrict__ M1,
                                                   float* __restrict__ PQ,
                                                   _Float16* __restrict__ Ah,
                                                   double* __restrict__ klsum) {
  const int w = threadIdx.x >> 6, l = threadIdx.x & 63;
  const int sub = l >> 5, d = l & 31;
  if (blockIdx.x < 512) {
    __shared__ float lm[8][DIM];
    float m = 0.0f;
#pragma unroll
    for (int i = 0; i < 4; ++i) {
      const int k = blockIdx.x * 32 + i * 8 + w * 2 + sub;
      const float c = cb[k * DIM + d];
      Bh[(size_t)k * 64 + d] = (_Float16)c;
      Bh[(size_t)k * 64 + 32 + d] = (_Float16)(c * c);
      m = fmaxf(m, fabsf(c));
    }
    lm[threadIdx.x >> 5][d] = m;
    __syncthreads();
    if (threadIdx.x < DIM) {
      float x = lm[0][threadIdx.x];
#pragma unroll
      for (int i = 1; i < 8; ++i) x = fmaxf(x, lm[i][threadIdx.x]);
      atomicMax((unsigned*)&M1[threadIdx.x], __float_as_uint(x));
    }
  } else {
    const int blk = blockIdx.x - 512;
    double kacc = 0.0;
#pragma unroll 1
    for (int i = 0; i < 4; ++i) {
      const int row = blk * 32 + i * 8 + w * 2 + sub;
      const int t = row >> 3, c = row & 7;
      const float mu = z[t * 512 + d * 8 + c];
      float lv = z[t * 512 + 256 + d * 8 + c];
      lv = fminf(fmaxf(lv, -30.0f), 20.0f);
      const float stdv = expf(0.5f * lv);
      const float iv = 1.0f / (stdv * stdv);   // identical to R2 expression
      const float p = mu * iv;
      const float q = 0.5f * (1.0f - iv);
      PQ[(size_t)row * 64 + d] = p;
      PQ[(size_t)row * 64 + 32 + d] = q;
      Ah[(size_t)row * 64 + d] = (_Float16)p;
      Ah[(size_t)row * 64 + 32 + d] = (_Float16)q;
      kacc += (double)(mu * mu + stdv * stdv - 1.0f - lv);
    }
#pragma unroll
    for (int off = 32; off > 0; off >>= 1) kacc += __shfl_down(kacc, off);
    __shared__ double wsum[4];
    if (l == 0) wsum[w] = kacc;
    __syncthreads();
    if (threadIdx.x == 0)
      atomicAdd(klsum, (wsum[0] + wsum[1]) + (wsum[2] + wsum[3]));
  }
}

// grid (RGRP=8, NKB=128): x = rowgroup (2048 rows), y = kblk (128 k).
// 4 waves x 512 rows each. B panel register-resident; no LDS, no barriers.
__global__ __launch_bounds__(256, 4) void filter_kernel(const _Float16* __restrict__ Ah,
                                                        const _Float16* __restrict__ Bh,
                                                        float* __restrict__ W1) {
  const int lane = threadIdx.x & 63;
  const int wave = threadIdx.x >> 6;
  const int c16 = lane & 15, quad = lane >> 4;
  const int kbase = blockIdx.y * KBLK;
  const int col0 = blockIdx.y * 2;
  const int rowbase0 = blockIdx.x * 2048 + wave * 512;

  // load B panel once: 8 tiles x (c, c^2) fragments = 64 VGPR
  half8 bx0[8], bx1[8];
#pragma unroll
  for (int t = 0; t < 8; ++t) {
    const size_t bb = (size_t)(kbase + t * 16 + c16) * 64 + quad * 8;
    bx0[t] = *(const half8*)(Bh + bb);
    bx1[t] = *(const half8*)(Bh + bb + 32);
  }

  const f32x4 fzero = {0.f, 0.f, 0.f, 0.f};
  const size_t astep = 16 * 64;                // halfs per rowtile
  size_t acur = (size_t)(rowbase0 + c16) * 64 + quad * 8;
  half8 u0 = *(const half8*)(Ah + acur);
  half8 u1 = *(const half8*)(Ah + acur + 32);

#pragma unroll 1
  for (int rt = 0; rt < NRT; ++rt) {
    half8 n0, n1;
    if (rt + 1 < NRT) {                        // prefetch next rowtile's A
      n0 = *(const half8*)(Ah + acur + astep);
      n1 = *(const half8*)(Ah + acur + astep + 32);
    }
    // col 0: tiles 0..3
    f32x4 m0 = __builtin_amdgcn_mfma_f32_16x16x32_f16(u0, bx0[0], fzero, 0, 0, 0);
    m0 = __builtin_amdgcn_mfma_f32_16x16x32_f16(u1, bx1[0], m0, 0, 0, 0);
#pragma unroll
    for (int t = 1; t < 4; ++t) {
      f32x4 h = __builtin_amdgcn_mfma_f32_16x16x32_f16(u0, bx0[t], fzero, 0, 0, 0);
      h = __builtin_amdgcn_mfma_f32_16x16x32_f16(u1, bx1[t], h, 0, 0, 0);
#pragma unroll
      for (int r = 0; r < 4; ++r) m0[r] = fmaxf(m0[r], h[r]);
    }
    // col 1: tiles 4..7
    f32x4 m1 = __builtin_amdgcn_mfma_f32_16x16x32_f16(u0, bx0[4], fzero, 0, 0, 0);
    m1 = __builtin_amdgcn_mfma_f32_16x16x32_f16(u1, bx1[4], m1, 0, 0, 0);
#pragma unroll
    for (int t = 5; t < 8; ++t) {
      f32x4 h = __builtin_amdgcn_mfma_f32_16x16x32_f16(u0, bx0[t], fzero, 0, 0, 0);
      h = __builtin_amdgcn_mfma_f32_16x16x32_f16(u1, bx1[t], h, 0, 0, 0);
#pragma unroll
      for (int r = 0; r < 4; ++r) m1[r] = fmaxf(m1[r], h[r]);
    }
    // fold c16 lanes (cols of the 16x16 tiles) -> per-row 64-k column max
#pragma unroll
    for (int mask = 1; mask <= 8; mask <<= 1) {
#pragma unroll
      for (int r = 0; r < 4; ++r) {
        m0[r] = fmaxf(m0[r], __shfl_xor(m0[r], mask));
        m1[r] = fmaxf(m1[r], __shfl_xor(m1[r], mask));
      }
    }
    if (c16 == 0) {
      const int rowo = rowbase0 + rt * 16 + quad * 4;  // C: row=quad*4+r
#pragma unroll
      for (int r = 0; r < 4; ++r) {
        W1[(size_t)col0 * NROWS + rowo + r] = m0[r];
        W1[(size_t)(col0 + 1) * NROWS + rowo + r] = m1[r];
      }
    }
    u0 = n0; u1 = n1; acur += astep;
  }
}

// exact fp32 score, p/q broadcast from LDS (identical formula to R2)
__device__ __forceinline__ float exact_score(const float4* __restrict__ cb4,
                                             const float4* __restrict__ spq,
                                             int k) {
  float s0 = 0.0f, s1 = 0.0f, s2 = 0.0f, s3 = 0.0f;
#pragma unroll
  for (int m = 0; m < 8; ++m) {
    const float4 cv = cb4[k * 8 + m];
    const float4 pv = spq[m];        // p[4m..4m+3]
    const float4 qv = spq[8 + m];    // q[4m..4m+3]
    s0 = fmaf(cv.x, fmaf(qv.x, cv.x, pv.x), s0);
    s1 = fmaf(cv.y, fmaf(qv.y, cv.y, pv.y), s1);
    s2 = fmaf(cv.z, fmaf(qv.z, cv.z, pv.z), s2);
    s3 = fmaf(cv.w, fmaf(qv.w, cv.w, pv.w), s3);
  }
  return (s0 + s1) + (s2 + s3);
}

// 1 wave per row; 4 rows per block. col = k>>6 (64 consecutive k per col).
// Seed E* by fully rescanning the argmax column, then full rescan of every
// column with w + Btot >= E*.  Rows XCD-chunk swizzled for W1 L2 locality.
__global__ __launch_bounds__(256, 4) void merge_kernel(const float* __restrict__ PQ,
                                                       const float* __restrict__ cb,
                                                       const float* __restrict__ W1,
                                                       const float* __restrict__ M1,
                                                       const double* __restrict__ klsum,
                                                       float* __restrict__ out0,
                                                       float* __restrict__ out1,
                                                       float* __restrict__ out2) {
  __shared__ float4 spq_s[4][16];
  const int lane = threadIdx.x & 63;
  const int wave = threadIdx.x >> 6;
  // bijective XCD-chunk swizzle: 4096 blocks = 8 x 512
  const int bswz = (blockIdx.x & 7) * 512 + (blockIdx.x >> 3);
  const int row = bswz * 4 + wave;

  if (lane < 16)
    spq_s[wave][lane] = ((const float4*)(PQ + (size_t)row * 64))[lane];
  __syncthreads();
  const float4* spq = spq_s[wave];
  const float4* __restrict__ cb4 = (const float4*)cb;

  // per-row rigorous bound S = sum |p|M1 + |q|M1^2
  float s = 0.0f;
  if (lane < DIM) {
    const float m1 = M1[lane];
    const float pd = ((const float*)spq)[lane];
    const float qd = ((const float*)spq)[32 + lane];
    s = fabsf(pd) * m1 + fabsf(qd) * m1 * m1;
  }
#pragma unroll
  for (int off = 1; off < 32; off <<= 1) s += __shfl_xor(s, off);
  const float Sn = __shfl(s, 0);

  // load 256 column maxima (layout [col][row]); col = i*64 + lane
  float w[4];
#pragma unroll
  for (int i = 0; i < 4; ++i)
    w[i] = W1[(size_t)(i * 64 + lane) * NROWS + row];
  float As = fmaxf(fmaxf(w[0], w[1]), fmaxf(w[2], w[3]));
#pragma unroll
  for (int off = 1; off < 64; off <<= 1) As = fmaxf(As, __shfl_xor(As, off));
  const float Btot = 1.05e-3f * Sn + 2e-5f * (fabsf(As) + 1.0f) + 1e-3f;

  // ---- seed: full exact rescan of (one) column achieving As ----
  int done_col = -1;
#pragma unroll
  for (int i = 0; i < 4; ++i) {
    if (done_col < 0) {
      const unsigned long long m = __ballot(w[i] == As);
      if (m) done_col = i * 64 + __builtin_ctzll(m);
    }
  }
  const int k0 = done_col * 64 + lane;     // 64 consecutive k, coalesced cb
  float best = exact_score(cb4, spq, k0);
  int bk = k0;
#pragma unroll
  for (int off = 1; off < 64; off <<= 1) {
    const float ov = __shfl_xor(best, off);
    const int ok = __shfl_xor(bk, off);
    if (ov > best || (ov == best && ok < bk)) { best = ov; bk = ok; }
  }
  const float Estar = best;   // exact score of a real k; all lanes agree

  // ---- full rescan of every other column that could still hold the max ----
#pragma unroll 1
  for (int i = 0; i < 4; ++i) {
    unsigned long long m = __ballot(w[i] + Btot >= Estar);
    if ((done_col >> 6) == i) m &= ~(1ull << (done_col & 63));
    while (m) {
      const int e = __builtin_ctzll(m);
      m &= m - 1;
      const int col = i * 64 + e;
      const int k = col * 64 + lane;
      const float sc = exact_score(cb4, spq, k);
      if (sc > best || (sc == best && k < bk)) { best = sc; bk = k; }
    }
  }
  // final cross-lane argmax, min-k on ties (numpy first-max)
#pragma unroll
  for (int off = 1; off < 64; off <<= 1) {
    const float ov = __shfl_xor(best, off);
    const int ok = __shfl_xor(bk, off);
    if (ov > best || (ov == best && ok < bk)) { best = ov; bk = ok; }
  }
  if (lane == 0) out2[row] = (float)bk;
  const int tt = row >> 3, cc = row & 7;
  if (lane < DIM) out0[tt * 256 + lane * 8 + cc] = cb[bk * DIM + lane];
  if (blockIdx.x == 0 && threadIdx.x == 0)
    out1[0] = (float)(klsum[0] * (1.4426 * 0.5) / (double)NROWS);
}

extern "C" void kernel_launch(void* const* d_in, const int* in_sizes, int n_in,
                              void* d_out, int out_size, void* d_ws, size_t ws_size,
                              hipStream_t stream) {
  const float* z  = (const float*)d_in[0];
  const float* cb = (const float*)d_in[2];   // d_in[1]=noise unused (STE cancels)

  char* ws = (char*)d_ws;
  float*      M1 = (float*)(ws + WS_M1);
  double* klsum  = (double*)(ws + WS_KL);
  float*      PQ = (float*)(ws + WS_PQ);
  _Float16*   Ah = (_Float16*)(ws + WS_AH);
  _Float16*   Bh = (_Float16*)(ws + WS_BH);
  float*      W1 = (float*)(ws + WS_W1);

  float* out0 = (float*)d_out;            // 524288
  float* out1 = out0 + 524288;            // 1
  float* out2 = out1 + 1;                 // 16384

  (void)hipMemsetAsync(ws, 0, 4096, stream);       // M1, klsum = 0
  prep_kernel<<<1024, 256, 0, stream>>>(cb, z, Bh, M1, PQ, Ah, klsum);
  dim3 fgrid(RGRP, NKB);
  filter_kernel<<<fgrid, 256, 0, stream>>>(Ah, Bh, W1);
  merge_kernel<<<NROWS / 4, 256, 0, stream>>>(PQ, cb, W1, M1, klsum,
                                              out0, out1, out2);
}

// Round 3
// 159.133 us; speedup vs baseline: 1.1073x; 1.1073x over previous
//
#include <hip/hip_runtime.h>
#include <math.h>

// ---------------------------------------------------------------------------
// GaussianQuant — MFMA-filtered argmax, R16.
// score[n,k] = sum_d p*c + q*c^2;  u=[p,q], v=[c,c^2], score = u.v  (K=64)
// fp16 HI-ONLY approx: |err| <= 1.05e-3*S (rigorous), S = sum |p|M1+|q|M1^2.
// R16 (vs R15 post-mortem): R15's consecutive-k columns forced a per-rowtile
// cross-lane shuffle fold (32 bpermute/rowtile -> ~27us of LDS-pipe per CU,
// MfmaUtil 18.6%). R16 restores R14's TEMPORAL columns: col = (split, c16),
// max accumulated across the split's 64 tiles in registers — zero cross-lane
// ops. Keeps R15's no-LDS register streaming, roles swapped:
//   - A resident per wave: 8 rowtiles (128 rows) = 16 half8 = 64 VGPR
//   - B streamed from L2 tile-by-tile (2x 16B loads, 1-tile prefetch)
//   - per tile: 8 independent (mfma,mfma) chains + 32 fmax (VALU pipe,
//     hidden under MFMA per m114); load:MFMA = 1:8
//   - ZERO LDS, ZERO barriers, ZERO shuffles in the hot loop
// Grid (32 rowgroups, 16 splits) = 512 blocks, 8 waves/CU. B-stream traffic
// 256 MB from L2 (~7.4us chip) under the 16.6us MFMA floor.
// prep (linear Bh) = R15 verbatim; merge = R14 verbatim (W1 [split][row][16]).
// ---------------------------------------------------------------------------

typedef _Float16 half8 __attribute__((ext_vector_type(8)));
typedef float f32x4 __attribute__((ext_vector_type(4)));

#define DIM 32
#define NROWS 16384
#define KSIZE 16384
#define NSPLIT 16
#define SPLITK 1024
#define NCOL 256

// ws layout (bytes); [0,4096) zeroed by memset each launch
#define WS_M1   0                       // 32 float (atomicMax targets)
#define WS_KL   256                     // 1 double (atomicAdd target)
#define WS_PQ   4096                    // 4 MB fp32 [row][64]
#define WS_AH   (WS_PQ + 4194304)       // 2 MB fp16 [row][64]
#define WS_BH   (WS_AH + 2097152)       // 2 MB fp16 [k][64] LINEAR
#define WS_W1   (WS_BH + 2097152)       // 16 MB fp32 [split][row][16]

// Fused prep, 1024 blocks: [0,512) pack codebook (linear) + per-dim max;
// [512,1024) compute p,q + fp16 pack + KL partial sum.
__global__ __launch_bounds__(256) void prep_kernel(const float* __restrict__ cb,
                                                   const float* __restrict__ z,
                                                   _Float16* __restrict__ Bh,
                                                   float* __restrict__ M1,
                                                   float* __restrict__ PQ,
                                                   _Float16* __restrict__ Ah,
                                                   double* __restrict__ klsum) {
  const int w = threadIdx.x >> 6, l = threadIdx.x & 63;
  const int sub = l >> 5, d = l & 31;
  if (blockIdx.x < 512) {
    __shared__ float lm[8][DIM];
    float m = 0.0f;
#pragma unroll
    for (int i = 0; i < 4; ++i) {
      const int k = blockIdx.x * 32 + i * 8 + w * 2 + sub;
      const float c = cb[k * DIM + d];
      Bh[(size_t)k * 64 + d] = (_Float16)c;
      Bh[(size_t)k * 64 + 32 + d] = (_Float16)(c * c);
      m = fmaxf(m, fabsf(c));
    }
    lm[threadIdx.x >> 5][d] = m;
    __syncthreads();
    if (threadIdx.x < DIM) {
      float x = lm[0][threadIdx.x];
#pragma unroll
      for (int i = 1; i < 8; ++i) x = fmaxf(x, lm[i][threadIdx.x]);
      atomicMax((unsigned*)&M1[threadIdx.x], __float_as_uint(x));
    }
  } else {
    const int blk = blockIdx.x - 512;
    double kacc = 0.0;
#pragma unroll 1
    for (int i = 0; i < 4; ++i) {
      const int row = blk * 32 + i * 8 + w * 2 + sub;
      const int t = row >> 3, c = row & 7;
      const float mu = z[t * 512 + d * 8 + c];
      float lv = z[t * 512 + 256 + d * 8 + c];
      lv = fminf(fmaxf(lv, -30.0f), 20.0f);
      const float stdv = expf(0.5f * lv);
      const float iv = 1.0f / (stdv * stdv);   // identical to R2 expression
      const float p = mu * iv;
      const float q = 0.5f * (1.0f - iv);
      PQ[(size_t)row * 64 + d] = p;
      PQ[(size_t)row * 64 + 32 + d] = q;
      Ah[(size_t)row * 64 + d] = (_Float16)p;
      Ah[(size_t)row * 64 + 32 + d] = (_Float16)q;
      kacc += (double)(mu * mu + stdv * stdv - 1.0f - lv);
    }
#pragma unroll
    for (int off = 32; off > 0; off >>= 1) kacc += __shfl_down(kacc, off);
    __shared__ double wsum[4];
    if (l == 0) wsum[w] = kacc;
    __syncthreads();
    if (threadIdx.x == 0)
      atomicAdd(klsum, (wsum[0] + wsum[1]) + (wsum[2] + wsum[3]));
  }
}

// grid (32, 16): x = rowgroup (512 rows), y = split (1024 k).
// 4 waves x 128 rows (8 rowtiles) each. A register-resident; B streamed
// from L2 with 1-tile prefetch. No LDS, no barriers, no cross-lane ops.
__global__ __launch_bounds__(256, 2) void filter_kernel(const _Float16* __restrict__ Ah,
                                                        const _Float16* __restrict__ Bh,
                                                        float* __restrict__ W1) {
  const int lane = threadIdx.x & 63;
  const int wave = threadIdx.x >> 6;
  const int c16 = lane & 15, quad = lane >> 4;
  const int split = blockIdx.y;
  const int rowbase = blockIdx.x * 512 + wave * 128;

  // load A panel once: 8 rowtiles x (p, q) fragments = 64 VGPR
  half8 u0[8], u1[8];
#pragma unroll
  for (int rt = 0; rt < 8; ++rt) {
    const size_t ab = (size_t)(rowbase + rt * 16 + c16) * 64 + quad * 8;
    u0[rt] = *(const half8*)(Ah + ab);
    u1[rt] = *(const half8*)(Ah + ab + 32);
  }

  float a1[8][4];
#pragma unroll
  for (int rt = 0; rt < 8; ++rt)
#pragma unroll
    for (int r = 0; r < 4; ++r) a1[rt][r] = -INFINITY;

  const f32x4 fzero = {0.f, 0.f, 0.f, 0.f};
  const _Float16* gB = Bh + (size_t)split * SPLITK * 64;  // 128 KB region

  half8 b0 = *(const half8*)(gB + c16 * 64 + quad * 8);
  half8 b1 = *(const half8*)(gB + c16 * 64 + quad * 8 + 32);

#pragma unroll 1
  for (int t = 0; t < 64; ++t) {
    half8 n0, n1;
    if (t < 63) {                      // prefetch next tile's B fragments
      const _Float16* nb = gB + (size_t)((t + 1) * 16 + c16) * 64 + quad * 8;
      n0 = *(const half8*)(nb);
      n1 = *(const half8*)(nb + 32);
    }
#pragma unroll
    for (int rt = 0; rt < 8; ++rt) {
      f32x4 h = __builtin_amdgcn_mfma_f32_16x16x32_f16(u0[rt], b0, fzero, 0, 0, 0);
      h = __builtin_amdgcn_mfma_f32_16x16x32_f16(u1[rt], b1, h, 0, 0, 0);
#pragma unroll
      for (int r = 0; r < 4; ++r) a1[rt][r] = fmaxf(a1[rt][r], h[r]);
    }
    b0 = n0; b1 = n1;
  }

  // W1 layout [split][row][16]: block-exclusive contiguous 32KB, no RMW
#pragma unroll
  for (int rt = 0; rt < 8; ++rt)
#pragma unroll
    for (int r = 0; r < 4; ++r) {
      const int row_r = rowbase + rt * 16 + quad * 4 + r;   // C: row=quad*4+r
      W1[((size_t)split * NROWS + row_r) * 16 + c16] = a1[rt][r];
    }
}

// exact fp32 score, p/q broadcast from LDS (identical formula to R2)
__device__ __forceinline__ float exact_score(const float4* __restrict__ cb4,
                                             const float4* __restrict__ spq,
                                             int k) {
  float s0 = 0.0f, s1 = 0.0f, s2 = 0.0f, s3 = 0.0f;
#pragma unroll
  for (int m = 0; m < 8; ++m) {
    const float4 cv = cb4[k * 8 + m];
    const float4 pv = spq[m];        // p[4m..4m+3]
    const float4 qv = spq[8 + m];    // q[4m..4m+3]
    s0 = fmaf(cv.x, fmaf(qv.x, cv.x, pv.x), s0);
    s1 = fmaf(cv.y, fmaf(qv.y, cv.y, pv.y), s1);
    s2 = fmaf(cv.z, fmaf(qv.z, cv.z, pv.z), s2);
    s3 = fmaf(cv.w, fmaf(qv.w, cv.w, pv.w), s3);
  }
  return (s0 + s1) + (s2 + s3);
}

// 1 wave per row; 4 rows per block. Seed E* by fully rescanning the argmax
// column, then full rescan of every column with w + Btot >= E*. (R14 verbatim)
__global__ __launch_bounds__(256, 4) void merge_kernel(const float* __restrict__ PQ,
                                                       const float* __restrict__ cb,
                                                       const float* __restrict__ W1,
                                                       const float* __restrict__ M1,
                                                       const double* __restrict__ klsum,
                                                       float* __restrict__ out0,
                                                       float* __restrict__ out1,
                                                       float* __restrict__ out2) {
  __shared__ float4 spq_s[4][16];
  const int lane = threadIdx.x & 63;
  const int wave = threadIdx.x >> 6;
  const int row = blockIdx.x * 4 + wave;

  if (lane < 16)
    spq_s[wave][lane] = ((const float4*)(PQ + (size_t)row * 64))[lane];
  __syncthreads();
  const float4* spq = spq_s[wave];
  const float4* __restrict__ cb4 = (const float4*)cb;

  // per-row rigorous bound S = sum |p|M1 + |q|M1^2
  float s = 0.0f;
  if (lane < DIM) {
    const float m1 = M1[lane];
    const float pd = ((const float*)spq)[lane];
    const float qd = ((const float*)spq)[32 + lane];
    s = fabsf(pd) * m1 + fabsf(qd) * m1 * m1;
  }
#pragma unroll
  for (int off = 1; off < 32; off <<= 1) s += __shfl_xor(s, off);
  const float Sn = __shfl(s, 0);

  // load 256 column maxima (layout [split][row][16]); col = i*64 + lane
  float w[4];
#pragma unroll
  for (int i = 0; i < 4; ++i)
    w[i] = W1[((size_t)(i * 4 + (lane >> 4)) * NROWS + row) * 16 + (lane & 15)];
  float As = fmaxf(fmaxf(w[0], w[1]), fmaxf(w[2], w[3]));
#pragma unroll
  for (int off = 1; off < 64; off <<= 1) As = fmaxf(As, __shfl_xor(As, off));
  const float Btot = 1.05e-3f * Sn + 2e-5f * (fabsf(As) + 1.0f) + 1e-3f;

  // ---- seed: full exact rescan of (one) column achieving As ----
  int done_col = -1;
#pragma unroll
  for (int i = 0; i < 4; ++i) {
    if (done_col < 0) {
      const unsigned long long m = __ballot(w[i] == As);
      if (m) done_col = i * 64 + __builtin_ctzll(m);
    }
  }
  const int k0 = (done_col >> 4) * SPLITK + lane * 16 + (done_col & 15);
  float best = exact_score(cb4, spq, k0);
  int bk = k0;
#pragma unroll
  for (int off = 1; off < 64; off <<= 1) {
    const float ov = __shfl_xor(best, off);
    const int ok = __shfl_xor(bk, off);
    if (ov > best || (ov == best && ok < bk)) { best = ov; bk = ok; }
  }
  const float Estar = best;   // exact score of a real k; all lanes agree

  // ---- full rescan of every other column that could still hold the max ----
#pragma unroll 1
  for (int i = 0; i < 4; ++i) {
    unsigned long long m = __ballot(w[i] + Btot >= Estar);
    if ((done_col >> 6) == i) m &= ~(1ull << (done_col & 63));
    while (m) {
      const int e = __builtin_ctzll(m);
      m &= m - 1;
      const int col = i * 64 + e;
      const int k = (col >> 4) * SPLITK + lane * 16 + (col & 15);
      const float sc = exact_score(cb4, spq, k);
      if (sc > best || (sc == best && k < bk)) { best = sc; bk = k; }
    }
  }
  // final cross-lane argmax, min-k on ties (numpy first-max)
#pragma unroll
  for (int off = 1; off < 64; off <<= 1) {
    const float ov = __shfl_xor(best, off);
    const int ok = __shfl_xor(bk, off);
    if (ov > best || (ov == best && ok < bk)) { best = ov; bk = ok; }
  }
  if (lane == 0) out2[row] = (float)bk;
  const int tt = row >> 3, cc = row & 7;
  if (lane < DIM) out0[tt * 256 + lane * 8 + cc] = cb[bk * DIM + lane];
  if (blockIdx.x == 0 && threadIdx.x == 0)
    out1[0] = (float)(klsum[0] * (1.4426 * 0.5) / (double)NROWS);
}

extern "C" void kernel_launch(void* const* d_in, const int* in_sizes, int n_in,
                              void* d_out, int out_size, void* d_ws, size_t ws_size,
                              hipStream_t stream) {
  const float* z  = (const float*)d_in[0];
  const float* cb = (const float*)d_in[2];   // d_in[1]=noise unused (STE cancels)

  char* ws = (char*)d_ws;
  float*      M1 = (float*)(ws + WS_M1);
  double* klsum  = (double*)(ws + WS_KL);
  float*      PQ = (float*)(ws + WS_PQ);
  _Float16*   Ah = (_Float16*)(ws + WS_AH);
  _Float16*   Bh = (_Float16*)(ws + WS_BH);
  float*      W1 = (float*)(ws + WS_W1);

  float* out0 = (float*)d_out;            // 524288
  float* out1 = out0 + 524288;            // 1
  float* out2 = out1 + 1;                 // 16384

  (void)hipMemsetAsync(ws, 0, 4096, stream);       // M1, klsum = 0
  prep_kernel<<<1024, 256, 0, stream>>>(cb, z, Bh, M1, PQ, Ah, klsum);
  dim3 fgrid(32, NSPLIT);
  filter_kernel<<<fgrid, 256, 0, stream>>>(Ah, Bh, W1);
  merge_kernel<<<NROWS / 4, 256, 0, stream>>>(PQ, cb, W1, M1, klsum,
                                              out0, out1, out2);
}

// Round 5
// 145.294 us; speedup vs baseline: 1.2128x; 1.0952x over previous
//
#include <hip/hip_runtime.h>
#include <math.h>

// ---------------------------------------------------------------------------
// GaussianQuant — MFMA-filtered argmax, R17b (complete file; R4 shipped a
// comment-only fragment with no kernel_launch symbol — harness error, mine).
// score[n,k] = sum_d p*c + q*c^2;  u=[p,q], v=[c,c^2], score = u.v  (K=64)
// fp16 HI-ONLY approx: |err| <= 1.05e-3*S (rigorous), S = sum |p|M1+|q|M1^2.
// R17 (vs R16 post-mortem): R16's filter was LATENCY-bound: prefetch depth
// 1 tile (~60 issue-cyc) vs ~250cyc L2 latency, at only 2 waves/SIMD
// (MfmaUtil 22%). R17 keeps the R16 dataflow (A register-resident, B
// streamed, temporal col=(split,c16), no LDS/barriers/shuffles) and fixes:
//   1. SW pipeline: B processed in tile-PAIRS (32 pairs/split), loads issued
//      2 full compute blocks (~620 wall cyc) ahead via named double-buffer
//      regs (no runtime-indexed arrays -> no scratch).
//   2. v_max3: acc = max(acc, max(h0,h1)) folds a pair in one VALU op;
//      reduction VALU halves (13.7 -> 6.8 us/CU), under the MFMA shadow.
// Loop bounds: prologue pairs 0,1; main tp=0..28 step 2 computes tp,tp+1 and
// loads tp+2,tp+3; epilogue computes pairs 30,31. Covers all 64 tiles.
// Floor: 8192 MFMA/CU x 4.85cyc = 16.6us. prep/merge = R16 verbatim.
// ---------------------------------------------------------------------------

typedef _Float16 half8 __attribute__((ext_vector_type(8)));
typedef float f32x4 __attribute__((ext_vector_type(4)));

#define DIM 32
#define NROWS 16384
#define KSIZE 16384
#define NSPLIT 16
#define SPLITK 1024
#define NCOL 256

// ws layout (bytes); [0,4096) zeroed by memset each launch
#define WS_M1   0                       // 32 float (atomicMax targets)
#define WS_KL   256                     // 1 double (atomicAdd target)
#define WS_PQ   4096                    // 4 MB fp32 [row][64]
#define WS_AH   (WS_PQ + 4194304)       // 2 MB fp16 [row][64]
#define WS_BH   (WS_AH + 2097152)       // 2 MB fp16 [k][64] LINEAR
#define WS_W1   (WS_BH + 2097152)       // 16 MB fp32 [split][row][16]

// Fused prep, 1024 blocks: [0,512) pack codebook (linear) + per-dim max;
// [512,1024) compute p,q + fp16 pack + KL partial sum.
__global__ __launch_bounds__(256) void prep_kernel(const float* __restrict__ cb,
                                                   const float* __restrict__ z,
                                                   _Float16* __restrict__ Bh,
                                                   float* __restrict__ M1,
                                                   float* __restrict__ PQ,
                                                   _Float16* __restrict__ Ah,
                                                   double* __restrict__ klsum) {
  const int w = threadIdx.x >> 6, l = threadIdx.x & 63;
  const int sub = l >> 5, d = l & 31;
  if (blockIdx.x < 512) {
    __shared__ float lm[8][DIM];
    float m = 0.0f;
#pragma unroll
    for (int i = 0; i < 4; ++i) {
      const int k = blockIdx.x * 32 + i * 8 + w * 2 + sub;
      const float c = cb[k * DIM + d];
      Bh[(size_t)k * 64 + d] = (_Float16)c;
      Bh[(size_t)k * 64 + 32 + d] = (_Float16)(c * c);
      m = fmaxf(m, fabsf(c));
    }
    lm[threadIdx.x >> 5][d] = m;
    __syncthreads();
    if (threadIdx.x < DIM) {
      float x = lm[0][threadIdx.x];
#pragma unroll
      for (int i = 1; i < 8; ++i) x = fmaxf(x, lm[i][threadIdx.x]);
      atomicMax((unsigned*)&M1[threadIdx.x], __float_as_uint(x));
    }
  } else {
    const int blk = blockIdx.x - 512;
    double kacc = 0.0;
#pragma unroll 1
    for (int i = 0; i < 4; ++i) {
      const int row = blk * 32 + i * 8 + w * 2 + sub;
      const int t = row >> 3, c = row & 7;
      const float mu = z[t * 512 + d * 8 + c];
      float lv = z[t * 512 + 256 + d * 8 + c];
      lv = fminf(fmaxf(lv, -30.0f), 20.0f);
      const float stdv = expf(0.5f * lv);
      const float iv = 1.0f / (stdv * stdv);   // identical to R2 expression
      const float p = mu * iv;
      const float q = 0.5f * (1.0f - iv);
      PQ[(size_t)row * 64 + d] = p;
      PQ[(size_t)row * 64 + 32 + d] = q;
      Ah[(size_t)row * 64 + d] = (_Float16)p;
      Ah[(size_t)row * 64 + 32 + d] = (_Float16)q;
      kacc += (double)(mu * mu + stdv * stdv - 1.0f - lv);
    }
#pragma unroll
    for (int off = 32; off > 0; off >>= 1) kacc += __shfl_down(kacc, off);
    __shared__ double wsum[4];
    if (l == 0) wsum[w] = kacc;
    __syncthreads();
    if (threadIdx.x == 0)
      atomicAdd(klsum, (wsum[0] + wsum[1]) + (wsum[2] + wsum[3]));
  }
}

// grid (32, 16): x = rowgroup (512 rows), y = split (1024 k).
// 4 waves x 128 rows (8 rowtiles) each. A register-resident; B streamed in
// tile-pairs with distance-2 SW pipeline. No LDS, no barriers, no shuffles.
__global__ __launch_bounds__(256, 2) void filter_kernel(const _Float16* __restrict__ Ah,
                                                        const _Float16* __restrict__ Bh,
                                                        float* __restrict__ W1) {
  const int lane = threadIdx.x & 63;
  const int wave = threadIdx.x >> 6;
  const int c16 = lane & 15, quad = lane >> 4;
  const int split = blockIdx.y;
  const int rowbase = blockIdx.x * 512 + wave * 128;

  // load A panel once: 8 rowtiles x (p, q) fragments = 64 VGPR
  half8 u0[8], u1[8];
#pragma unroll
  for (int rt = 0; rt < 8; ++rt) {
    const size_t ab = (size_t)(rowbase + rt * 16 + c16) * 64 + quad * 8;
    u0[rt] = *(const half8*)(Ah + ab);
    u1[rt] = *(const half8*)(Ah + ab + 32);
  }

  float a1[8][4];
#pragma unroll
  for (int rt = 0; rt < 8; ++rt)
#pragma unroll
    for (int r = 0; r < 4; ++r) a1[rt][r] = -INFINITY;

  const f32x4 fzero = {0.f, 0.f, 0.f, 0.f};
  // per-lane B base; tile t at +t*1024 halfs (q-part +32), pair tp at +tp*2048
  const _Float16* gB = Bh + (size_t)split * SPLITK * 64 + c16 * 64 + quad * 8;

#define LOADP(P0, P1, Q0, Q1, tp)                                   \
  P0 = *(const half8*)(gB + (size_t)(tp) * 2048);                   \
  P1 = *(const half8*)(gB + (size_t)(tp) * 2048 + 32);              \
  Q0 = *(const half8*)(gB + (size_t)(tp) * 2048 + 1024);            \
  Q1 = *(const half8*)(gB + (size_t)(tp) * 2048 + 1024 + 32);

#define COMPUTEP(P0, P1, Q0, Q1)                                              \
  _Pragma("unroll") for (int rt = 0; rt < 8; ++rt) {                          \
    f32x4 h0 = __builtin_amdgcn_mfma_f32_16x16x32_f16(u0[rt], P0, fzero, 0, 0, 0); \
    h0 = __builtin_amdgcn_mfma_f32_16x16x32_f16(u1[rt], P1, h0, 0, 0, 0);     \
    f32x4 h1 = __builtin_amdgcn_mfma_f32_16x16x32_f16(u0[rt], Q0, fzero, 0, 0, 0); \
    h1 = __builtin_amdgcn_mfma_f32_16x16x32_f16(u1[rt], Q1, h1, 0, 0, 0);     \
    _Pragma("unroll") for (int r = 0; r < 4; ++r)                             \
      a1[rt][r] = fmaxf(a1[rt][r], fmaxf(h0[r], h1[r]));                      \
  }

  half8 x0, x1, y0, y1;      // pair buffer A
  half8 X0, X1, Y0, Y1;      // pair buffer B
  LOADP(x0, x1, y0, y1, 0)
  LOADP(X0, X1, Y0, Y1, 1)

#pragma unroll 1
  for (int tp = 0; tp < 30; tp += 2) {   // computes pairs 0..29
    half8 nx0, nx1, ny0, ny1, nX0, nX1, nY0, nY1;
    LOADP(nx0, nx1, ny0, ny1, tp + 2)    // issue 2 compute-blocks ahead
    COMPUTEP(x0, x1, y0, y1)
    LOADP(nX0, nX1, nY0, nY1, tp + 3)
    COMPUTEP(X0, X1, Y0, Y1)
    x0 = nx0; x1 = nx1; y0 = ny0; y1 = ny1;
    X0 = nX0; X1 = nX1; Y0 = nY0; Y1 = nY1;
  }
  COMPUTEP(x0, x1, y0, y1)               // pair 30
  COMPUTEP(X0, X1, Y0, Y1)               // pair 31
#undef LOADP
#undef COMPUTEP

  // W1 layout [split][row][16]: block-exclusive contiguous 32KB, no RMW
#pragma unroll
  for (int rt = 0; rt < 8; ++rt)
#pragma unroll
    for (int r = 0; r < 4; ++r) {
      const int row_r = rowbase + rt * 16 + quad * 4 + r;   // C: row=quad*4+r
      W1[((size_t)split * NROWS + row_r) * 16 + c16] = a1[rt][r];
    }
}

// exact fp32 score, p/q broadcast from LDS (identical formula to R2)
__device__ __forceinline__ float exact_score(const float4* __restrict__ cb4,
                                             const float4* __restrict__ spq,
                                             int k) {
  float s0 = 0.0f, s1 = 0.0f, s2 = 0.0f, s3 = 0.0f;
#pragma unroll
  for (int m = 0; m < 8; ++m) {
    const float4 cv = cb4[k * 8 + m];
    const float4 pv = spq[m];        // p[4m..4m+3]
    const float4 qv = spq[8 + m];    // q[4m..4m+3]
    s0 = fmaf(cv.x, fmaf(qv.x, cv.x, pv.x), s0);
    s1 = fmaf(cv.y, fmaf(qv.y, cv.y, pv.y), s1);
    s2 = fmaf(cv.z, fmaf(qv.z, cv.z, pv.z), s2);
    s3 = fmaf(cv.w, fmaf(qv.w, cv.w, pv.w), s3);
  }
  return (s0 + s1) + (s2 + s3);
}

// 1 wave per row; 4 rows per block. Seed E* by fully rescanning the argmax
// column, then full rescan of every column with w + Btot >= E*. (R16 verbatim)
__global__ __launch_bounds__(256, 4) void merge_kernel(const float* __restrict__ PQ,
                                                       const float* __restrict__ cb,
                                                       const float* __restrict__ W1,
                                                       const float* __restrict__ M1,
                                                       const double* __restrict__ klsum,
                                                       float* __restrict__ out0,
                                                       float* __restrict__ out1,
                                                       float* __restrict__ out2) {
  __shared__ float4 spq_s[4][16];
  const int lane = threadIdx.x & 63;
  const int wave = threadIdx.x >> 6;
  const int row = blockIdx.x * 4 + wave;

  if (lane < 16)
    spq_s[wave][lane] = ((const float4*)(PQ + (size_t)row * 64))[lane];
  __syncthreads();
  const float4* spq = spq_s[wave];
  const float4* __restrict__ cb4 = (const float4*)cb;

  // per-row rigorous bound S = sum |p|M1 + |q|M1^2
  float s = 0.0f;
  if (lane < DIM) {
    const float m1 = M1[lane];
    const float pd = ((const float*)spq)[lane];
    const float qd = ((const float*)spq)[32 + lane];
    s = fabsf(pd) * m1 + fabsf(qd) * m1 * m1;
  }
#pragma unroll
  for (int off = 1; off < 32; off <<= 1) s += __shfl_xor(s, off);
  const float Sn = __shfl(s, 0);

  // load 256 column maxima (layout [split][row][16]); col = i*64 + lane
  float w[4];
#pragma unroll
  for (int i = 0; i < 4; ++i)
    w[i] = W1[((size_t)(i * 4 + (lane >> 4)) * NROWS + row) * 16 + (lane & 15)];
  float As = fmaxf(fmaxf(w[0], w[1]), fmaxf(w[2], w[3]));
#pragma unroll
  for (int off = 1; off < 64; off <<= 1) As = fmaxf(As, __shfl_xor(As, off));
  const float Btot = 1.05e-3f * Sn + 2e-5f * (fabsf(As) + 1.0f) + 1e-3f;

  // ---- seed: full exact rescan of (one) column achieving As ----
  int done_col = -1;
#pragma unroll
  for (int i = 0; i < 4; ++i) {
    if (done_col < 0) {
      const unsigned long long m = __ballot(w[i] == As);
      if (m) done_col = i * 64 + __builtin_ctzll(m);
    }
  }
  const int k0 = (done_col >> 4) * SPLITK + lane * 16 + (done_col & 15);
  float best = exact_score(cb4, spq, k0);
  int bk = k0;
#pragma unroll
  for (int off = 1; off < 64; off <<= 1) {
    const float ov = __shfl_xor(best, off);
    const int ok = __shfl_xor(bk, off);
    if (ov > best || (ov == best && ok < bk)) { best = ov; bk = ok; }
  }
  const float Estar = best;   // exact score of a real k; all lanes agree

  // ---- full rescan of every other column that could still hold the max ----
#pragma unroll 1
  for (int i = 0; i < 4; ++i) {
    unsigned long long m = __ballot(w[i] + Btot >= Estar);
    if ((done_col >> 6) == i) m &= ~(1ull << (done_col & 63));
    while (m) {
      const int e = __builtin_ctzll(m);
      m &= m - 1;
      const int col = i * 64 + e;
      const int k = (col >> 4) * SPLITK + lane * 16 + (col & 15);
      const float sc = exact_score(cb4, spq, k);
      if (sc > best || (sc == best && k < bk)) { best = sc; bk = k; }
    }
  }
  // final cross-lane argmax, min-k on ties (numpy first-max)
#pragma unroll
  for (int off = 1; off < 64; off <<= 1) {
    const float ov = __shfl_xor(best, off);
    const int ok = __shfl_xor(bk, off);
    if (ov > best || (ov == best && ok < bk)) { best = ov; bk = ok; }
  }
  if (lane == 0) out2[row] = (float)bk;
  const int tt = row >> 3, cc = row & 7;
  if (lane < DIM) out0[tt * 256 + lane * 8 + cc] = cb[bk * DIM + lane];
  if (blockIdx.x == 0 && threadIdx.x == 0)
    out1[0] = (float)(klsum[0] * (1.4426 * 0.5) / (double)NROWS);
}

extern "C" void kernel_launch(void* const* d_in, const int* in_sizes, int n_in,
                              void* d_out, int out_size, void* d_ws, size_t ws_size,
                              hipStream_t stream) {
  const float* z  = (const float*)d_in[0];
  const float* cb = (const float*)d_in[2];   // d_in[1]=noise unused (STE cancels)

  char* ws = (char*)d_ws;
  float*      M1 = (float*)(ws + WS_M1);
  double* klsum  = (double*)(ws + WS_KL);
  float*      PQ = (float*)(ws + WS_PQ);
  _Float16*   Ah = (_Float16*)(ws + WS_AH);
  _Float16*   Bh = (_Float16*)(ws + WS_BH);
  float*      W1 = (float*)(ws + WS_W1);

  float* out0 = (float*)d_out;            // 524288
  float* out1 = out0 + 524288;            // 1
  float* out2 = out1 + 1;                 // 16384

  (void)hipMemsetAsync(ws, 0, 4096, stream);       // M1, klsum = 0
  prep_kernel<<<1024, 256, 0, stream>>>(cb, z, Bh, M1, PQ, Ah, klsum);
  dim3 fgrid(32, NSPLIT);
  filter_kernel<<<fgrid, 256, 0, stream>>>(Ah, Bh, W1);
  merge_kernel<<<NROWS / 4, 256, 0, stream>>>(PQ, cb, W1, M1, klsum,
                                              out0, out1, out2);
}

// Round 6
// 134.781 us; speedup vs baseline: 1.3074x; 1.0780x over previous
//
#include <hip/hip_runtime.h>
#include <math.h>

// ---------------------------------------------------------------------------
// GaussianQuant — MFMA-filtered argmax, R18.
// score[n,k] = sum_d p*c + q*c^2;  u=[p,q], v=[c,c^2], score = u.v  (K=64)
// fp16 HI-ONLY approx, rigorous per-k error:
//   err_k <= 1.05e-3 * (||p||2*||c_k||2 + ||q||2*||c_k^2||2)   (Cauchy-Schwarz)
// R18 (vs R17b post-mortem): register-streaming filter capped at 44us by
// 2 waves/SIMD occupancy; REVERT filter to the verified R14 structure
// (global_load_lds dbuf, pre-swizzled Bh, 4 blocks/CU, ~31us).
// NEW: per-COLUMN prune bound in merge. Old bound used S = sum|p|M1+|q|M1^2
// (M1 = global per-dim max, ||M1|| ~ 24) -> Btot ~ O(1) -> tens of candidate
// columns/row -> merge est. ~35us of serial exact rescans (hidden below the
// top-5 cut). New: prep computes cn1[col]=max_k ||c_k||, cn2[col]=max_k
// ||c_k^2|| (max ~6.5); merge prunes with Btot_col = 1.05e-3*(||p||*cn1 +
// ||q||*cn2) + 2e-5*(|A*|+1) + 1e-3. ~3.7x tighter -> ~5-10x fewer
// candidates. Soundness: exact_k <= approx_k + err_k <= w[col] + Btot_col.
// ---------------------------------------------------------------------------

typedef _Float16 half8 __attribute__((ext_vector_type(8)));
typedef float f32x4 __attribute__((ext_vector_type(4)));

#define DIM 32
#define NROWS 16384
#define KSIZE 16384
#define NSPLIT 16
#define SPLITK 1024
#define NCOL 256

// ws layout (bytes); [0,4096) zeroed by memset each launch
#define WS_M1   0                       // 32 float (atomicMax targets)
#define WS_KL   256                     // 1 double (atomicAdd target)
#define WS_CN1  512                     // 256 float (atomicMax: max ||c_k||)
#define WS_CN2  1536                    // 256 float (atomicMax: max ||c_k^2||)
#define WS_PQ   4096                    // 4 MB fp32 [row][64]
#define WS_AH   (WS_PQ + 4194304)       // 2 MB fp16 [row][64]
#define WS_BH   (WS_AH + 2097152)       // 2 MB fp16 [k][64] PRE-SWIZZLED
#define WS_W1   (WS_BH + 2097152)       // 16 MB fp32 [split][row][16]

// Fused prep, 1024 blocks: [0,512) pack codebook (swizzled) + per-dim max +
// per-column norm maxima; [512,1024) compute p,q + fp16 pack + KL partial.
__global__ __launch_bounds__(256) void prep_kernel(const float* __restrict__ cb,
                                                   const float* __restrict__ z,
                                                   _Float16* __restrict__ Bh,
                                                   float* __restrict__ M1,
                                                   float* __restrict__ CN1,
                                                   float* __restrict__ CN2,
                                                   float* __restrict__ PQ,
                                                   _Float16* __restrict__ Ah,
                                                   double* __restrict__ klsum) {
  const int w = threadIdx.x >> 6, l = threadIdx.x & 63;
  const int sub = l >> 5, d = l & 31;
  if (blockIdx.x < 512) {
    __shared__ float lm[8][DIM];
    float m = 0.0f;
#pragma unroll
    for (int i = 0; i < 4; ++i) {
      const int k = blockIdx.x * 32 + i * 8 + w * 2 + sub;
      const float c = cb[k * DIM + d];
      // swizzled slot layout: logical slot s (8 halfs) stored at s ^ (k&7)
      const int key = k & 7;
      const int sc = (d >> 3) ^ key;          // c-part: logical slot d>>3
      const int sq = (4 + (d >> 3)) ^ key;    // c^2-part: logical slot 4+d>>3
      Bh[(size_t)k * 64 + sc * 8 + (d & 7)] = (_Float16)c;
      Bh[(size_t)k * 64 + sq * 8 + (d & 7)] = (_Float16)(c * c);
      m = fmaxf(m, fabsf(c));
      // per-k norms -> per-column maxima (col = (k>>10)*16 + (k&15))
      float s2 = c * c, s4 = c * c * c * c;
#pragma unroll
      for (int mask = 1; mask <= 16; mask <<= 1) {
        s2 += __shfl_xor(s2, mask);
        s4 += __shfl_xor(s4, mask);
      }
      if (d == 0) {
        const int col = (k >> 10) * 16 + (k & 15);
        atomicMax((unsigned*)&CN1[col], __float_as_uint(sqrtf(s2)));
        atomicMax((unsigned*)&CN2[col], __float_as_uint(sqrtf(s4)));
      }
    }
    lm[threadIdx.x >> 5][d] = m;
    __syncthreads();
    if (threadIdx.x < DIM) {
      float x = lm[0][threadIdx.x];
#pragma unroll
      for (int i = 1; i < 8; ++i) x = fmaxf(x, lm[i][threadIdx.x]);
      atomicMax((unsigned*)&M1[threadIdx.x], __float_as_uint(x));
    }
  } else {
    const int blk = blockIdx.x - 512;
    double kacc = 0.0;
#pragma unroll 1
    for (int i = 0; i < 4; ++i) {
      const int row = blk * 32 + i * 8 + w * 2 + sub;
      const int t = row >> 3, c = row & 7;
      const float mu = z[t * 512 + d * 8 + c];
      float lv = z[t * 512 + 256 + d * 8 + c];
      lv = fminf(fmaxf(lv, -30.0f), 20.0f);
      const float stdv = expf(0.5f * lv);
      const float iv = 1.0f / (stdv * stdv);   // identical to R2 expression
      const float p = mu * iv;
      const float q = 0.5f * (1.0f - iv);
      PQ[(size_t)row * 64 + d] = p;
      PQ[(size_t)row * 64 + 32 + d] = q;
      Ah[(size_t)row * 64 + d] = (_Float16)p;
      Ah[(size_t)row * 64 + 32 + d] = (_Float16)q;
      kacc += (double)(mu * mu + stdv * stdv - 1.0f - lv);
    }
#pragma unroll
    for (int off = 32; off > 0; off >>= 1) kacc += __shfl_down(kacc, off);
    __shared__ double wsum[4];
    if (l == 0) wsum[w] = kacc;
    __syncthreads();
    if (threadIdx.x == 0)
      atomicAdd(klsum, (wsum[0] + wsum[1]) + (wsum[2] + wsum[3]));
  }
}

// async global->LDS, 16B per lane; dest must be linear in lane order.
__device__ __forceinline__ void gload_lds16(const _Float16* g, _Float16* l) {
  __builtin_amdgcn_global_load_lds(
      (__attribute__((address_space(1))) void*)(g),
      (__attribute__((address_space(3))) void*)(l), 16, 0, 0);
}

// grid (64, 16): x = rowgroup (256 rows), y = split. 4 waves x 64 rows each.
// B staged through 2 x 16 KB LDS buffers via global_load_lds, 1 barrier/chunk.
// (R14 verbatim — verified ~31us.)
__global__ __launch_bounds__(256, 4) void filter_kernel(const _Float16* __restrict__ Ah,
                                                        const _Float16* __restrict__ Bh,
                                                        float* __restrict__ W1) {
  __shared__ _Float16 sB[2][8192];   // 2 x 16 KB
  const int tid = threadIdx.x;
  const int lane = tid & 63;
  const int wave = tid >> 6;
  const int split = blockIdx.y;
  const int rowbase = blockIdx.x * 256 + wave * 64;   // 4 rowtiles of 16
  const int c16 = lane & 15, quad = lane >> 4;

  const _Float16* gB = Bh + (size_t)split * SPLITK * 64;  // 128 KB region

  // async-stage chunk 0 -> buf 0 (linear copy: Bh pre-swizzled in prep)
#pragma unroll
  for (int j = 0; j < 4; ++j)
    gload_lds16(gB + j * 2048 + tid * 8, &sB[0][j * 2048 + tid * 8]);

  half8 uh0[4], uh1[4];
#pragma unroll
  for (int rt = 0; rt < 4; ++rt) {
    const size_t abase = (size_t)(rowbase + rt * 16 + c16) * 64 + quad * 8;
    uh0[rt] = *(const half8*)(Ah + abase);
    uh1[rt] = *(const half8*)(Ah + abase + 32);
  }

  float a1[4][4];
#pragma unroll
  for (int rt = 0; rt < 4; ++rt)
#pragma unroll
    for (int r = 0; r < 4; ++r) a1[rt][r] = -INFINITY;

  const f32x4 fzero = {0.f, 0.f, 0.f, 0.f};
  // swizzled read offsets (halfs): row c16, physical slot = logical ^ (c16&7)
  const int key = c16 & 7;
  const int rs0h = c16 * 64 + (quad ^ key) * 8;         // p-part (slots 0-3)
  const int rs1h = c16 * 64 + ((quad + 4) ^ key) * 8;   // q-part (slots 4-7)

  __syncthreads();   // chunk 0 landed (compiler drains vmcnt before barrier)

#pragma unroll 1
  for (int ch = 0; ch < 8; ++ch) {
    if (ch < 7) {    // issue next chunk into the idle buffer (async)
      const _Float16* src = gB + (size_t)(ch + 1) * 8192;
      _Float16* dst = &sB[(ch + 1) & 1][0];
#pragma unroll
      for (int j = 0; j < 4; ++j)
        gload_lds16(src + j * 2048 + tid * 8, dst + j * 2048 + tid * 8);
    }
    const _Float16* buf = &sB[ch & 1][0];
#pragma unroll 1
    for (int tp = 0; tp < 4; ++tp) {          // 4 tile-pairs per chunk
      const _Float16* b0 = buf + (2 * tp) * 1024;
      const _Float16* b1 = b0 + 1024;
      const half8 x0 = *(const half8*)(b0 + rs0h);
      const half8 x1 = *(const half8*)(b0 + rs1h);
      const half8 y0 = *(const half8*)(b1 + rs0h);
      const half8 y1 = *(const half8*)(b1 + rs1h);
#pragma unroll
      for (int rt = 0; rt < 4; ++rt) {
        f32x4 h0 = __builtin_amdgcn_mfma_f32_16x16x32_f16(uh0[rt], x0, fzero, 0, 0, 0);
        h0 = __builtin_amdgcn_mfma_f32_16x16x32_f16(uh1[rt], x1, h0, 0, 0, 0);
        f32x4 h1 = __builtin_amdgcn_mfma_f32_16x16x32_f16(uh0[rt], y0, fzero, 0, 0, 0);
        h1 = __builtin_amdgcn_mfma_f32_16x16x32_f16(uh1[rt], y1, h1, 0, 0, 0);
#pragma unroll
        for (int r = 0; r < 4; ++r)
          a1[rt][r] = fmaxf(fmaxf(h0[r], h1[r]), a1[rt][r]);   // v_max3
      }
    }
    __syncthreads();  // all waves done with buf; next chunk landed (vmcnt 0)
  }

  // W1 layout [split][row][16]: block-exclusive contiguous 16KB, no RMW
#pragma unroll
  for (int rt = 0; rt < 4; ++rt)
#pragma unroll
    for (int r = 0; r < 4; ++r) {
      const int row_r = rowbase + rt * 16 + quad * 4 + r;   // C: row=quad*4+r
      W1[((size_t)split * NROWS + row_r) * 16 + c16] = a1[rt][r];
    }
}

// exact fp32 score, p/q broadcast from LDS (identical formula to R2)
__device__ __forceinline__ float exact_score(const float4* __restrict__ cb4,
                                             const float4* __restrict__ spq,
                                             int k) {
  float s0 = 0.0f, s1 = 0.0f, s2 = 0.0f, s3 = 0.0f;
#pragma unroll
  for (int m = 0; m < 8; ++m) {
    const float4 cv = cb4[k * 8 + m];
    const float4 pv = spq[m];        // p[4m..4m+3]
    const float4 qv = spq[8 + m];    // q[4m..4m+3]
    s0 = fmaf(cv.x, fmaf(qv.x, cv.x, pv.x), s0);
    s1 = fmaf(cv.y, fmaf(qv.y, cv.y, pv.y), s1);
    s2 = fmaf(cv.z, fmaf(qv.z, cv.z, pv.z), s2);
    s3 = fmaf(cv.w, fmaf(qv.w, cv.w, pv.w), s3);
  }
  return (s0 + s1) + (s2 + s3);
}

// 1 wave per row; 4 rows per block. Seed E* by fully rescanning the argmax
// column, then full rescan of every column with w + Btot_col >= E*.
// Btot_col uses per-column codebook norm maxima (Cauchy-Schwarz bound).
__global__ __launch_bounds__(256, 4) void merge_kernel(const float* __restrict__ PQ,
                                                       const float* __restrict__ cb,
                                                       const float* __restrict__ W1,
                                                       const float* __restrict__ CN1,
                                                       const float* __restrict__ CN2,
                                                       const double* __restrict__ klsum,
                                                       float* __restrict__ out0,
                                                       float* __restrict__ out1,
                                                       float* __restrict__ out2) {
  __shared__ float4 spq_s[4][16];
  const int lane = threadIdx.x & 63;
  const int wave = threadIdx.x >> 6;
  const int row = blockIdx.x * 4 + wave;

  if (lane < 16)
    spq_s[wave][lane] = ((const float4*)(PQ + (size_t)row * 64))[lane];
  __syncthreads();
  const float4* spq = spq_s[wave];
  const float4* __restrict__ cb4 = (const float4*)cb;

  // per-row norms ||p||2, ||q||2
  float sp = 0.0f, sq = 0.0f;
  if (lane < DIM) {
    const float pd = ((const float*)spq)[lane];
    const float qd = ((const float*)spq)[32 + lane];
    sp = pd * pd;
    sq = qd * qd;
  }
#pragma unroll
  for (int off = 1; off < 32; off <<= 1) {
    sp += __shfl_xor(sp, off);
    sq += __shfl_xor(sq, off);
  }
  const float pn = sqrtf(__shfl(sp, 0));
  const float qn = sqrtf(__shfl(sq, 0));

  // load 256 column maxima (layout [split][row][16]); col = i*64 + lane
  float w[4];
#pragma unroll
  for (int i = 0; i < 4; ++i)
    w[i] = W1[((size_t)(i * 4 + (lane >> 4)) * NROWS + row) * 16 + (lane & 15)];
  float As = fmaxf(fmaxf(w[0], w[1]), fmaxf(w[2], w[3]));
#pragma unroll
  for (int off = 1; off < 64; off <<= 1) As = fmaxf(As, __shfl_xor(As, off));
  const float slack = 2e-5f * (fabsf(As) + 1.0f) + 1e-3f;

  // per-column rigorous bounds: Btot_col = 1.05e-3*(pn*cn1 + qn*cn2) + slack
  float bt[4];
#pragma unroll
  for (int i = 0; i < 4; ++i) {
    const int col = i * 64 + lane;
    bt[i] = 1.05e-3f * (pn * CN1[col] + qn * CN2[col]) + slack;
  }

  // ---- seed: full exact rescan of (one) column achieving As ----
  int done_col = -1;
#pragma unroll
  for (int i = 0; i < 4; ++i) {
    if (done_col < 0) {
      const unsigned long long m = __ballot(w[i] == As);
      if (m) done_col = i * 64 + __builtin_ctzll(m);
    }
  }
  const int k0 = (done_col >> 4) * SPLITK + lane * 16 + (done_col & 15);
  float best = exact_score(cb4, spq, k0);
  int bk = k0;
#pragma unroll
  for (int off = 1; off < 64; off <<= 1) {
    const float ov = __shfl_xor(best, off);
    const int ok = __shfl_xor(bk, off);
    if (ov > best || (ov == best && ok < bk)) { best = ov; bk = ok; }
  }
  const float Estar = best;   // exact score of a real k; all lanes agree

  // ---- full rescan of every other column that could still hold the max ----
#pragma unroll 1
  for (int i = 0; i < 4; ++i) {
    unsigned long long m = __ballot(w[i] + bt[i] >= Estar);
    if ((done_col >> 6) == i) m &= ~(1ull << (done_col & 63));
    while (m) {
      const int e = __builtin_ctzll(m);
      m &= m - 1;
      const int col = i * 64 + e;
      const int k = (col >> 4) * SPLITK + lane * 16 + (col & 15);
      const float sc = exact_score(cb4, spq, k);
      if (sc > best || (sc == best && k < bk)) { best = sc; bk = k; }
    }
  }
  // final cross-lane argmax, min-k on ties (numpy first-max)
#pragma unroll
  for (int off = 1; off < 64; off <<= 1) {
    const float ov = __shfl_xor(best, off);
    const int ok = __shfl_xor(bk, off);
    if (ov > best || (ov == best && ok < bk)) { best = ov; bk = ok; }
  }
  if (lane == 0) out2[row] = (float)bk;
  const int tt = row >> 3, cc = row & 7;
  if (lane < DIM) out0[tt * 256 + lane * 8 + cc] = cb[bk * DIM + lane];
  if (blockIdx.x == 0 && threadIdx.x == 0)
    out1[0] = (float)(klsum[0] * (1.4426 * 0.5) / (double)NROWS);
}

extern "C" void kernel_launch(void* const* d_in, const int* in_sizes, int n_in,
                              void* d_out, int out_size, void* d_ws, size_t ws_size,
                              hipStream_t stream) {
  const float* z  = (const float*)d_in[0];
  const float* cb = (const float*)d_in[2];   // d_in[1]=noise unused (STE cancels)

  char* ws = (char*)d_ws;
  float*      M1 = (float*)(ws + WS_M1);
  double* klsum  = (double*)(ws + WS_KL);
  float*     CN1 = (float*)(ws + WS_CN1);
  float*     CN2 = (float*)(ws + WS_CN2);
  float*      PQ = (float*)(ws + WS_PQ);
  _Float16*   Ah = (_Float16*)(ws + WS_AH);
  _Float16*   Bh = (_Float16*)(ws + WS_BH);
  float*      W1 = (float*)(ws + WS_W1);

  float* out0 = (float*)d_out;            // 524288
  float* out1 = out0 + 524288;            // 1
  float* out2 = out1 + 1;                 // 16384

  (void)hipMemsetAsync(ws, 0, 4096, stream);   // M1, klsum, CN1, CN2 = 0
  prep_kernel<<<1024, 256, 0, stream>>>(cb, z, Bh, M1, CN1, CN2, PQ, Ah, klsum);
  dim3 fgrid(64, NSPLIT);
  filter_kernel<<<fgrid, 256, 0, stream>>>(Ah, Bh, W1);
  merge_kernel<<<NROWS / 4, 256, 0, stream>>>(PQ, cb, W1, CN1, CN2, klsum,
                                              out0, out1, out2);
}

// Round 7
// 133.734 us; speedup vs baseline: 1.3177x; 1.0078x over previous
//
#include <hip/hip_runtime.h>
#include <math.h>

// ---------------------------------------------------------------------------
// GaussianQuant — MFMA-filtered argmax, R19.
// score[n,k] = sum_d p*c + q*c^2;  u=[p,q], v=[c,c^2], score = u.v  (K=64)
// fp16 HI-ONLY approx, rigorous per-k error:
//   err_k <= 1.05e-3 * (||p||2*||c_k||2 + ||q||2*||c_k^2||2)   (Cauchy-Schwarz)
// R19 (vs R18 post-mortem): R18's prune tightening was a perfect null ->
// merge rescans are negligible; filter (est. 31us vs 16.6us MFMA floor) is
// the remaining modelable lever. Per-chunk arithmetic: 1024 MFMA/CU (4966cy)
// vs 256 ds_read_b128 (~3072cy LDS-pipe) + 32 barrier-events/CU = the ~47%
// overhead. R19 amortizes:
//   - 8 rowtiles/wave (A = 16 half8 = 64 VGPR resident, as in R17b):
//     ds_read per MFMA 0.25 -> 0.125; MFMA per barrier doubles.
//   - 32KB chunks, 4 chunks/split, dbuf 64KB, 2 blocks/CU: stage latency
//     hidden under 2x compute; barriers/block 8 -> 4.
//   - grid (32 rowgroups, 16 splits); W1 write region still block-exclusive.
// W1 packed fp16 (16->8MB HBM): store max(a1,-65504) (kills -inf; high side
// rounds down <= 4.88e-4 rel); merge adds 5e-4*|w| to the per-column bound.
// prep = R18 verbatim; merge = R18 + fp16 W1 + bound term.
// ---------------------------------------------------------------------------

typedef _Float16 half8 __attribute__((ext_vector_type(8)));
typedef float f32x4 __attribute__((ext_vector_type(4)));

#define DIM 32
#define NROWS 16384
#define KSIZE 16384
#define NSPLIT 16
#define SPLITK 1024
#define NCOL 256

// ws layout (bytes); [0,4096) zeroed by memset each launch
#define WS_M1   0                       // 32 float (atomicMax targets)
#define WS_KL   256                     // 1 double (atomicAdd target)
#define WS_CN1  512                     // 256 float (atomicMax: max ||c_k||)
#define WS_CN2  1536                    // 256 float (atomicMax: max ||c_k^2||)
#define WS_PQ   4096                    // 4 MB fp32 [row][64]
#define WS_AH   (WS_PQ + 4194304)       // 2 MB fp16 [row][64]
#define WS_BH   (WS_AH + 2097152)       // 2 MB fp16 [k][64] PRE-SWIZZLED
#define WS_W1   (WS_BH + 2097152)       // 8 MB fp16 [split][row][16]

// Fused prep, 1024 blocks: [0,512) pack codebook (swizzled) + per-dim max +
// per-column norm maxima; [512,1024) compute p,q + fp16 pack + KL partial.
__global__ __launch_bounds__(256) void prep_kernel(const float* __restrict__ cb,
                                                   const float* __restrict__ z,
                                                   _Float16* __restrict__ Bh,
                                                   float* __restrict__ M1,
                                                   float* __restrict__ CN1,
                                                   float* __restrict__ CN2,
                                                   float* __restrict__ PQ,
                                                   _Float16* __restrict__ Ah,
                                                   double* __restrict__ klsum) {
  const int w = threadIdx.x >> 6, l = threadIdx.x & 63;
  const int sub = l >> 5, d = l & 31;
  if (blockIdx.x < 512) {
    __shared__ float lm[8][DIM];
    float m = 0.0f;
#pragma unroll
    for (int i = 0; i < 4; ++i) {
      const int k = blockIdx.x * 32 + i * 8 + w * 2 + sub;
      const float c = cb[k * DIM + d];
      // swizzled slot layout: logical slot s (8 halfs) stored at s ^ (k&7)
      const int key = k & 7;
      const int sc = (d >> 3) ^ key;          // c-part: logical slot d>>3
      const int sq = (4 + (d >> 3)) ^ key;    // c^2-part: logical slot 4+d>>3
      Bh[(size_t)k * 64 + sc * 8 + (d & 7)] = (_Float16)c;
      Bh[(size_t)k * 64 + sq * 8 + (d & 7)] = (_Float16)(c * c);
      m = fmaxf(m, fabsf(c));
      // per-k norms -> per-column maxima (col = (k>>10)*16 + (k&15))
      float s2 = c * c, s4 = c * c * c * c;
#pragma unroll
      for (int mask = 1; mask <= 16; mask <<= 1) {
        s2 += __shfl_xor(s2, mask);
        s4 += __shfl_xor(s4, mask);
      }
      if (d == 0) {
        const int col = (k >> 10) * 16 + (k & 15);
        atomicMax((unsigned*)&CN1[col], __float_as_uint(sqrtf(s2)));
        atomicMax((unsigned*)&CN2[col], __float_as_uint(sqrtf(s4)));
      }
    }
    lm[threadIdx.x >> 5][d] = m;
    __syncthreads();
    if (threadIdx.x < DIM) {
      float x = lm[0][threadIdx.x];
#pragma unroll
      for (int i = 1; i < 8; ++i) x = fmaxf(x, lm[i][threadIdx.x]);
      atomicMax((unsigned*)&M1[threadIdx.x], __float_as_uint(x));
    }
  } else {
    const int blk = blockIdx.x - 512;
    double kacc = 0.0;
#pragma unroll 1
    for (int i = 0; i < 4; ++i) {
      const int row = blk * 32 + i * 8 + w * 2 + sub;
      const int t = row >> 3, c = row & 7;
      const float mu = z[t * 512 + d * 8 + c];
      float lv = z[t * 512 + 256 + d * 8 + c];
      lv = fminf(fmaxf(lv, -30.0f), 20.0f);
      const float stdv = expf(0.5f * lv);
      const float iv = 1.0f / (stdv * stdv);   // identical to R2 expression
      const float p = mu * iv;
      const float q = 0.5f * (1.0f - iv);
      PQ[(size_t)row * 64 + d] = p;
      PQ[(size_t)row * 64 + 32 + d] = q;
      Ah[(size_t)row * 64 + d] = (_Float16)p;
      Ah[(size_t)row * 64 + 32 + d] = (_Float16)q;
      kacc += (double)(mu * mu + stdv * stdv - 1.0f - lv);
    }
#pragma unroll
    for (int off = 32; off > 0; off >>= 1) kacc += __shfl_down(kacc, off);
    __shared__ double wsum[4];
    if (l == 0) wsum[w] = kacc;
    __syncthreads();
    if (threadIdx.x == 0)
      atomicAdd(klsum, (wsum[0] + wsum[1]) + (wsum[2] + wsum[3]));
  }
}

// async global->LDS, 16B per lane; dest must be linear in lane order.
__device__ __forceinline__ void gload_lds16(const _Float16* g, _Float16* l) {
  __builtin_amdgcn_global_load_lds(
      (__attribute__((address_space(1))) void*)(g),
      (__attribute__((address_space(3))) void*)(l), 16, 0, 0);
}

// grid (32, 16): x = rowgroup (512 rows), y = split. 4 waves x 128 rows each
// (8 rowtiles, A resident = 64 VGPR). B staged through 2 x 32 KB LDS buffers
// (16 tiles/chunk) via global_load_lds; 4 chunks, 1 barrier each.
__global__ __launch_bounds__(256, 2) void filter_kernel(const _Float16* __restrict__ Ah,
                                                        const _Float16* __restrict__ Bh,
                                                        _Float16* __restrict__ W1) {
  __shared__ _Float16 sB[2][16384];   // 2 x 32 KB
  const int tid = threadIdx.x;
  const int lane = tid & 63;
  const int wave = tid >> 6;
  const int split = blockIdx.y;
  const int rowbase = blockIdx.x * 512 + wave * 128;   // 8 rowtiles of 16
  const int c16 = lane & 15, quad = lane >> 4;

  const _Float16* gB = Bh + (size_t)split * SPLITK * 64;  // 128 KB region

  // async-stage chunk 0 -> buf 0 (linear copy: Bh pre-swizzled in prep)
#pragma unroll
  for (int j = 0; j < 8; ++j)
    gload_lds16(gB + j * 2048 + tid * 8, &sB[0][j * 2048 + tid * 8]);

  half8 uh0[8], uh1[8];
#pragma unroll
  for (int rt = 0; rt < 8; ++rt) {
    const size_t abase = (size_t)(rowbase + rt * 16 + c16) * 64 + quad * 8;
    uh0[rt] = *(const half8*)(Ah + abase);
    uh1[rt] = *(const half8*)(Ah + abase + 32);
  }

  float a1[8][4];
#pragma unroll
  for (int rt = 0; rt < 8; ++rt)
#pragma unroll
    for (int r = 0; r < 4; ++r) a1[rt][r] = -INFINITY;

  const f32x4 fzero = {0.f, 0.f, 0.f, 0.f};
  // swizzled read offsets (halfs): row c16, physical slot = logical ^ (c16&7)
  const int key = c16 & 7;
  const int rs0h = c16 * 64 + (quad ^ key) * 8;         // p-part (slots 0-3)
  const int rs1h = c16 * 64 + ((quad + 4) ^ key) * 8;   // q-part (slots 4-7)

  __syncthreads();   // chunk 0 landed (compiler drains vmcnt before barrier)

#pragma unroll 1
  for (int ch = 0; ch < 4; ++ch) {
    if (ch < 3) {    // issue next chunk into the idle buffer (async)
      const _Float16* src = gB + (size_t)(ch + 1) * 16384;
      _Float16* dst = &sB[(ch + 1) & 1][0];
#pragma unroll
      for (int j = 0; j < 8; ++j)
        gload_lds16(src + j * 2048 + tid * 8, dst + j * 2048 + tid * 8);
    }
    const _Float16* buf = &sB[ch & 1][0];
#pragma unroll 1
    for (int tp = 0; tp < 8; ++tp) {          // 8 tile-pairs per chunk
      const _Float16* b0 = buf + (2 * tp) * 1024;
      const _Float16* b1 = b0 + 1024;
      const half8 x0 = *(const half8*)(b0 + rs0h);
      const half8 x1 = *(const half8*)(b0 + rs1h);
      const half8 y0 = *(const half8*)(b1 + rs0h);
      const half8 y1 = *(const half8*)(b1 + rs1h);
#pragma unroll
      for (int rt = 0; rt < 8; ++rt) {
        f32x4 h0 = __builtin_amdgcn_mfma_f32_16x16x32_f16(uh0[rt], x0, fzero, 0, 0, 0);
        h0 = __builtin_amdgcn_mfma_f32_16x16x32_f16(uh1[rt], x1, h0, 0, 0, 0);
        f32x4 h1 = __builtin_amdgcn_mfma_f32_16x16x32_f16(uh0[rt], y0, fzero, 0, 0, 0);
        h1 = __builtin_amdgcn_mfma_f32_16x16x32_f16(uh1[rt], y1, h1, 0, 0, 0);
#pragma unroll
        for (int r = 0; r < 4; ++r)
          a1[rt][r] = fmaxf(fmaxf(h0[r], h1[r]), a1[rt][r]);   // v_max3
      }
    }
    __syncthreads();  // all waves done with buf; next chunk landed (vmcnt 0)
  }

  // W1 fp16 [split][row][16]: block-exclusive contiguous 16KB, no RMW.
  // Low-clamp kills -inf (sound over-estimate); high-side rounding covered
  // by merge's 5e-4*|w| bound term.
#pragma unroll
  for (int rt = 0; rt < 8; ++rt)
#pragma unroll
    for (int r = 0; r < 4; ++r) {
      const int row_r = rowbase + rt * 16 + quad * 4 + r;   // C: row=quad*4+r
      W1[((size_t)split * NROWS + row_r) * 16 + c16] =
          (_Float16)fmaxf(a1[rt][r], -65504.0f);
    }
}

// exact fp32 score, p/q broadcast from LDS (identical formula to R2)
__device__ __forceinline__ float exact_score(const float4* __restrict__ cb4,
                                             const float4* __restrict__ spq,
                                             int k) {
  float s0 = 0.0f, s1 = 0.0f, s2 = 0.0f, s3 = 0.0f;
#pragma unroll
  for (int m = 0; m < 8; ++m) {
    const float4 cv = cb4[k * 8 + m];
    const float4 pv = spq[m];        // p[4m..4m+3]
    const float4 qv = spq[8 + m];    // q[4m..4m+3]
    s0 = fmaf(cv.x, fmaf(qv.x, cv.x, pv.x), s0);
    s1 = fmaf(cv.y, fmaf(qv.y, cv.y, pv.y), s1);
    s2 = fmaf(cv.z, fmaf(qv.z, cv.z, pv.z), s2);
    s3 = fmaf(cv.w, fmaf(qv.w, cv.w, pv.w), s3);
  }
  return (s0 + s1) + (s2 + s3);
}

// 1 wave per row; 4 rows per block. Seed E* by fully rescanning the argmax
// column, then full rescan of every column with w + Btot_col >= E*.
// Btot_col = C-S bound + slack + 5e-4*|w| (fp16 W1 rounding).
__global__ __launch_bounds__(256, 4) void merge_kernel(const float* __restrict__ PQ,
                                                       const float* __restrict__ cb,
                                                       const _Float16* __restrict__ W1,
                                                       const float* __restrict__ CN1,
                                                       const float* __restrict__ CN2,
                                                       const double* __restrict__ klsum,
                                                       float* __restrict__ out0,
                                                       float* __restrict__ out1,
                                                       float* __restrict__ out2) {
  __shared__ float4 spq_s[4][16];
  const int lane = threadIdx.x & 63;
  const int wave = threadIdx.x >> 6;
  const int row = blockIdx.x * 4 + wave;

  if (lane < 16)
    spq_s[wave][lane] = ((const float4*)(PQ + (size_t)row * 64))[lane];
  __syncthreads();
  const float4* spq = spq_s[wave];
  const float4* __restrict__ cb4 = (const float4*)cb;

  // per-row norms ||p||2, ||q||2
  float sp = 0.0f, sq = 0.0f;
  if (lane < DIM) {
    const float pd = ((const float*)spq)[lane];
    const float qd = ((const float*)spq)[32 + lane];
    sp = pd * pd;
    sq = qd * qd;
  }
#pragma unroll
  for (int off = 1; off < 32; off <<= 1) {
    sp += __shfl_xor(sp, off);
    sq += __shfl_xor(sq, off);
  }
  const float pn = sqrtf(__shfl(sp, 0));
  const float qn = sqrtf(__shfl(sq, 0));

  // load 256 column maxima (fp16, layout [split][row][16]); col = i*64 + lane
  float w[4];
#pragma unroll
  for (int i = 0; i < 4; ++i)
    w[i] = (float)W1[((size_t)(i * 4 + (lane >> 4)) * NROWS + row) * 16 + (lane & 15)];
  float As = fmaxf(fmaxf(w[0], w[1]), fmaxf(w[2], w[3]));
#pragma unroll
  for (int off = 1; off < 64; off <<= 1) As = fmaxf(As, __shfl_xor(As, off));
  const float slack = 2e-5f * (fabsf(As) + 1.0f) + 1e-3f;

  // per-column rigorous bounds + fp16-rounding term
  float bt[4];
#pragma unroll
  for (int i = 0; i < 4; ++i) {
    const int col = i * 64 + lane;
    bt[i] = 1.05e-3f * (pn * CN1[col] + qn * CN2[col]) + slack
            + 5e-4f * fabsf(w[i]);
  }

  // ---- seed: full exact rescan of (one) column achieving As ----
  int done_col = -1;
#pragma unroll
  for (int i = 0; i < 4; ++i) {
    if (done_col < 0) {
      const unsigned long long m = __ballot(w[i] == As);
      if (m) done_col = i * 64 + __builtin_ctzll(m);
    }
  }
  const int k0 = (done_col >> 4) * SPLITK + lane * 16 + (done_col & 15);
  float best = exact_score(cb4, spq, k0);
  int bk = k0;
#pragma unroll
  for (int off = 1; off < 64; off <<= 1) {
    const float ov = __shfl_xor(best, off);
    const int ok = __shfl_xor(bk, off);
    if (ov > best || (ov == best && ok < bk)) { best = ov; bk = ok; }
  }
  const float Estar = best;   // exact score of a real k; all lanes agree

  // ---- full rescan of every other column that could still hold the max ----
#pragma unroll 1
  for (int i = 0; i < 4; ++i) {
    unsigned long long m = __ballot(w[i] + bt[i] >= Estar);
    if ((done_col >> 6) == i) m &= ~(1ull << (done_col & 63));
    while (m) {
      const int e = __builtin_ctzll(m);
      m &= m - 1;
      const int col = i * 64 + e;
      const int k = (col >> 4) * SPLITK + lane * 16 + (col & 15);
      const float sc = exact_score(cb4, spq, k);
      if (sc > best || (sc == best && k < bk)) { best = sc; bk = k; }
    }
  }
  // final cross-lane argmax, min-k on ties (numpy first-max)
#pragma unroll
  for (int off = 1; off < 64; off <<= 1) {
    const float ov = __shfl_xor(best, off);
    const int ok = __shfl_xor(bk, off);
    if (ov > best || (ov == best && ok < bk)) { best = ov; bk = ok; }
  }
  if (lane == 0) out2[row] = (float)bk;
  const int tt = row >> 3, cc = row & 7;
  if (lane < DIM) out0[tt * 256 + lane * 8 + cc] = cb[bk * DIM + lane];
  if (blockIdx.x == 0 && threadIdx.x == 0)
    out1[0] = (float)(klsum[0] * (1.4426 * 0.5) / (double)NROWS);
}

extern "C" void kernel_launch(void* const* d_in, const int* in_sizes, int n_in,
                              void* d_out, int out_size, void* d_ws, size_t ws_size,
                              hipStream_t stream) {
  const float* z  = (const float*)d_in[0];
  const float* cb = (const float*)d_in[2];   // d_in[1]=noise unused (STE cancels)

  char* ws = (char*)d_ws;
  float*      M1 = (float*)(ws + WS_M1);
  double* klsum  = (double*)(ws + WS_KL);
  float*     CN1 = (float*)(ws + WS_CN1);
  float*     CN2 = (float*)(ws + WS_CN2);
  float*      PQ = (float*)(ws + WS_PQ);
  _Float16*   Ah = (_Float16*)(ws + WS_AH);
  _Float16*   Bh = (_Float16*)(ws + WS_BH);
  _Float16*   W1 = (_Float16*)(ws + WS_W1);

  float* out0 = (float*)d_out;            // 524288
  float* out1 = out0 + 524288;            // 1
  float* out2 = out1 + 1;                 // 16384

  (void)hipMemsetAsync(ws, 0, 4096, stream);   // M1, klsum, CN1, CN2 = 0
  prep_kernel<<<1024, 256, 0, stream>>>(cb, z, Bh, M1, CN1, CN2, PQ, Ah, klsum);
  dim3 fgrid(32, NSPLIT);
  filter_kernel<<<fgrid, 256, 0, stream>>>(Ah, Bh, W1);
  merge_kernel<<<NROWS / 4, 256, 0, stream>>>(PQ, cb, W1, CN1, CN2, klsum,
                                              out0, out1, out2);
}